// Round 7
// baseline (569.617 us; speedup 1.0000x reference)
//
#include <hip/hip_runtime.h>
#include <hip/hip_bf16.h>
#include <math.h>

#define N_CAND 524288
#define RB     128
#define NBLK   (N_CAND / RB)     // 4096
#define EMB    128
#define HID    256
#define BGR    2048

#define OUT_XS  262144                      // offset of X_states in out (floats)
#define OUT_P   (262144 + 134217728)        // offset of probs in out (floats)

typedef __attribute__((ext_vector_type(4))) float f32x4;
typedef __attribute__((ext_vector_type(8))) short bf16x8;
typedef __attribute__((ext_vector_type(4))) short bf16x4;
typedef unsigned short u16;

__device__ __forceinline__ u16 f2bf(float f) {
  union { float f; unsigned u; } x; x.f = f;
  unsigned u = x.u;
  return (u16)((u + 0x7fffu + ((u >> 16) & 1u)) >> 16);   // RNE
}
__device__ __forceinline__ float bf2f(u16 h) {
  union { unsigned u; float f; } x; x.u = ((unsigned)h) << 16;
  return x.f;
}

// Raw barrier: waits LDS ops only (lgkmcnt), does NOT drain vmcnt.
// Global stores (X_states) keep flowing under later phases.
__device__ __forceinline__ void bar_lgkm() {
  __builtin_amdgcn_sched_barrier(0);
  asm volatile("s_waitcnt lgkmcnt(0)" ::: "memory");
  __builtin_amdgcn_sched_barrier(0);
  __builtin_amdgcn_s_barrier();
  __builtin_amdgcn_sched_barrier(0);
}
__device__ __forceinline__ void bar_only() {
  __builtin_amdgcn_sched_barrier(0);
  __builtin_amdgcn_s_barrier();
  __builtin_amdgcn_sched_barrier(0);
}

// ---- K0: convert W1/W2/W3 (f32, [k][n]) -> wt bf16 transposed [m][n][k] ----
__global__ void k_prep(const float* __restrict__ W1, const float* __restrict__ W2,
                       const float* __restrict__ W3, u16* __restrict__ wt) {
  const int b = blockIdx.x;
  const int m = b >> 8;          // which matrix
  const int n = b & 255;         // output unit (row of Wt)
  const int k = threadIdx.x;     // input unit
  const float* W = (m == 0) ? W1 : ((m == 1) ? W2 : W3);
  wt[m * 65536 + n * 256 + k] = f2bf(W[k * 256 + n]);
}

// ---- K1: fused X-concat/X_states write + 3-layer bf16 MFMA MLP + head ----
// 512 threads (8 waves), RB=128 rows. Wave grid 4n x 2r: wave owns
// 64n x 64r, acc[4][4] = 64 AGPR. B-read duplication 4x (LDS 3.2 GB),
// weight duplication 2x (L2 3.1 GB) -- balances LDS vs L2 pipes.
// Full (row&15) chunk-XOR swizzle. Raw lgkm-only barriers: X_states
// stores are never drained at a barrier. launch_bounds(512,4): 128-reg
// unified cap (64 arch + 64 acc), 2 blocks/CU.
__global__ __launch_bounds__(512, 4) void k_main(
    const float* __restrict__ g_emb, const float* __restrict__ cand,
    const int* __restrict__ bidx,
    const float* __restrict__ b1, const float* __restrict__ b2,
    const float* __restrict__ b3, const float* __restrict__ Wf,
    const float* __restrict__ bfp, const u16* __restrict__ wt,
    float* __restrict__ out)
{
  __shared__ __align__(16) u16 hbuf[RB * HID];   // 64 KB, chunk-XOR swizzled
  __shared__ float bias_s[3 * HID];
  __shared__ float wf_s[HID];
  __shared__ float bf_s;

  const int tid = threadIdx.x;
  const int r0  = blockIdx.x * RB;

  if (tid < HID) {
    bias_s[tid]           = b1[tid];
    bias_s[HID + tid]     = b2[tid];
    bias_s[2 * HID + tid] = b3[tid];
    wf_s[tid]             = Wf[tid];
    if (tid == 0) bf_s = bfp[0];
  }

  // ---- stage X (concat) into LDS bf16 swizzled; write X_states f32 ----
  {
    const int kc   = tid & 31;    // 16B chunk (8 elems) within the 256-col row
    const int row0 = tid >> 5;    // 0..15
    char* l0 = (char*)hbuf;
    int bpre[8];
    #pragma unroll
    for (int i = 0; i < 8; ++i)
      bpre[i] = bidx[r0 + row0 + i * 16];   // break dependent-load chain
    #pragma unroll
    for (int i = 0; i < 8; ++i) {
      const int row = row0 + i * 16;        // 0..127
      const int r   = r0 + row;
      const float* src;
      if (kc < 16) {
        src = g_emb + (size_t)bpre[i] * EMB + kc * 8;
      } else {
        src = cand + (size_t)r * EMB + (kc - 16) * 8;
      }
      f32x4 v0 = *(const f32x4*)(src);
      f32x4 v1 = *(const f32x4*)(src + 4);
      float* dst = out + OUT_XS + (size_t)r * (2 * EMB) + kc * 8;
      *(f32x4*)dst       = v0;   // async: never waited before a barrier
      *(f32x4*)(dst + 4) = v1;
      bf16x8 hv;
      hv[0] = (short)f2bf(v0.x); hv[1] = (short)f2bf(v0.y);
      hv[2] = (short)f2bf(v0.z); hv[3] = (short)f2bf(v0.w);
      hv[4] = (short)f2bf(v1.x); hv[5] = (short)f2bf(v1.y);
      hv[6] = (short)f2bf(v1.z); hv[7] = (short)f2bf(v1.w);
      *(bf16x8*)(l0 + row * 512 + ((kc * 16) ^ ((row & 15) << 4))) = hv;
    }
  }
  bar_lgkm();

  // ---- 3 MFMA layers, in place ----
  const int lane = tid & 63;
  const int w    = tid >> 6;          // 0..7
  const int ml   = lane & 15;
  const int g    = lane >> 4;         // 0..3
  const int wn0  = (w & 3) * 64;      // n-offset: 4 tiles of 16
  const int wr0  = (w >> 2) * 64;     // r-offset: 4 tiles of 16

  const int swz    = ml << 4;                 // row-swizzle ((rf*16+ml)&15 == ml)
  const int bofs   = (g * 16) ^ swz;          // k-chunk xor per lane
  char* const hb   = (char*)hbuf;
  char* const hbr  = hb + (size_t)(wr0 + ml) * 512;   // B-read base

  #pragma unroll
  for (int L = 0; L < 3; ++L) {
    const char* wl  = (const char*)wt + L * 131072 + (size_t)(wn0 + ml) * 512 + g * 16;
    const float* bs = bias_s + L * HID;

    f32x4 acc[4][4];   // [nf][rf] = 64 AGPR
    #pragma unroll
    for (int nf = 0; nf < 4; ++nf)
      #pragma unroll
      for (int rf = 0; rf < 4; ++rf)
        acc[nf][rf] = (f32x4){0.f, 0.f, 0.f, 0.f};

    __builtin_amdgcn_s_setprio(1);
    #pragma unroll
    for (int ks = 0; ks < 8; ++ks) {
      bf16x8 a[4];
      #pragma unroll
      for (int nf = 0; nf < 4; ++nf)
        a[nf] = *(const bf16x8*)(wl + nf * 8192 + ks * 64);          // weights (L2)
      #pragma unroll
      for (int rh = 0; rh < 2; ++rh) {
        bf16x8 bq[2];
        #pragma unroll
        for (int rj = 0; rj < 2; ++rj)
          bq[rj] = *(const bf16x8*)(hbr + (rh * 2 + rj) * 8192 + ((ks * 64) ^ bofs));
        #pragma unroll
        for (int nf = 0; nf < 4; ++nf)
          #pragma unroll
          for (int rj = 0; rj < 2; ++rj)
            acc[nf][rh * 2 + rj] = __builtin_amdgcn_mfma_f32_16x16x32_bf16(
                a[nf], bq[rj], acc[nf][rh * 2 + rj], 0, 0, 0);
      }
    }
    __builtin_amdgcn_s_setprio(0);
    // every wave's ds_reads are consumed by its MFMAs before it can reach
    // the barrier -> plain barrier suffices before in-place overwrite.
    bar_only();

    // epilogue: +bias, relu, ->bf16, packed b64 swizzled write (in place)
    #pragma unroll
    for (int nf = 0; nf < 4; ++nf) {
      const int n0 = wn0 + nf * 16 + g * 4;
      const f32x4 bb = *(const f32x4*)(bs + n0);
      #pragma unroll
      for (int rf = 0; rf < 4; ++rf) {
        const int r = wr0 + rf * 16 + ml;
        bf16x4 hv;
        #pragma unroll
        for (int q = 0; q < 4; ++q) {
          float x = acc[nf][rf][q] + bb[q];
          x = fmaxf(x, 0.f);
          hv[q] = (short)f2bf(x);
        }
        *(bf16x4*)(hb + r * 512 + ((n0 * 2) ^ swz)) = hv;
      }
    }
    bar_lgkm();
  }

  // ---- head: logits = h3 @ Wf + bf ; e = exp(logit)  (FULL 256 k!) ----
  {
    const int row  = tid >> 2;   // 0..127
    const int part = tid & 3;
    const int  swr = (row & 15) << 4;
    float sum = 0.f;
    #pragma unroll
    for (int i = 0; i < 8; ++i) {
      const int kc = part * 8 + i;            // 0..31: all 32 chunks
      bf16x8 hv = *(const bf16x8*)(hb + row * 512 + ((kc * 16) ^ swr));
      #pragma unroll
      for (int j = 0; j < 8; ++j)
        sum += bf2f((u16)hv[j]) * wf_s[kc * 8 + j];
    }
    sum += __shfl_xor(sum, 1);
    sum += __shfl_xor(sum, 2);
    if (part == 0) {
      const float logit = sum + bf_s;
      out[OUT_P + (size_t)(r0 + row)] = __expf(logit);
    }
  }
}

// ---- K2: denom[b] = segment_sum(e) via binary search (sorted batch_idx) ----
__global__ void k_denom(const float* __restrict__ e, const int* __restrict__ bidx,
                        float* __restrict__ denom)
{
  const int b = blockIdx.x;
  int lo = 0, hi = N_CAND;
  while (lo < hi) { int m = (lo + hi) >> 1; if (bidx[m] < b) lo = m + 1; else hi = m; }
  int lo2 = lo, hi2 = N_CAND;
  while (lo2 < hi2) { int m = (lo2 + hi2) >> 1; if (bidx[m] < b + 1) lo2 = m + 1; else hi2 = m; }
  float s = 0.f;
  for (int i = lo + (int)threadIdx.x; i < lo2; i += 64) s += e[i];
  #pragma unroll
  for (int off = 32; off > 0; off >>= 1) s += __shfl_down(s, off);
  if (threadIdx.x == 0) denom[b] = s;
}

// ---- K3: probs = e / denom[bidx] (in place) + g_emb copy ----
__global__ void k_post(const float* __restrict__ g_emb, const int* __restrict__ bidx,
                       const float* __restrict__ denom, float* __restrict__ out)
{
  const int i = blockIdx.x * 256 + threadIdx.x;
  const float e = out[OUT_P + (size_t)i];
  out[OUT_P + (size_t)i] = e / denom[bidx[i]];
  if (i < BGR * EMB) out[i] = g_emb[i];
}

extern "C" void kernel_launch(void* const* d_in, const int* in_sizes, int n_in,
                              void* d_out, int out_size, void* d_ws, size_t ws_size,
                              hipStream_t stream)
{
  const float* g_emb = (const float*)d_in[0];
  const float* cand  = (const float*)d_in[1];
  const float* W1    = (const float*)d_in[2];
  const float* b1    = (const float*)d_in[3];
  const float* W2    = (const float*)d_in[4];
  const float* b2    = (const float*)d_in[5];
  const float* W3    = (const float*)d_in[6];
  const float* b3    = (const float*)d_in[7];
  const float* Wf    = (const float*)d_in[8];
  const float* bfp   = (const float*)d_in[9];
  const int*   bidx  = (const int*)d_in[10];
  float* out = (float*)d_out;

  u16*   wt    = (u16*)d_ws;                                 // 3 * 128 KB bf16
  float* denom = (float*)((char*)d_ws + 3 * 65536 * 2);      // 2048 f32

  k_prep <<<768, 256, 0, stream>>>(W1, W2, W3, wt);
  k_main <<<NBLK, 512, 0, stream>>>(g_emb, cand, bidx, b1, b2, b3, Wf, bfp, wt, out);
  k_denom<<<BGR, 64, 0, stream>>>(out + OUT_P, bidx, denom);
  k_post <<<N_CAND / 256, 256, 0, stream>>>(g_emb, bidx, denom, out);
}

// Round 8
// 342.184 us; speedup vs baseline: 1.6646x; 1.6646x over previous
//
#include <hip/hip_runtime.h>
#include <hip/hip_bf16.h>
#include <math.h>

#define N_CAND 524288
#define RB     128
#define NBLK   (N_CAND / RB)     // 4096
#define EMB    128
#define HID    256
#define BGR    2048

#define OUT_XS  262144                      // offset of X_states in out (floats)
#define OUT_P   (262144 + 134217728)        // offset of probs in out (floats)

typedef __attribute__((ext_vector_type(4))) float f32x4;
typedef __attribute__((ext_vector_type(8))) short bf16x8;
typedef __attribute__((ext_vector_type(4))) short bf16x4;
typedef unsigned short u16;

__device__ __forceinline__ u16 f2bf(float f) {
  union { float f; unsigned u; } x; x.f = f;
  unsigned u = x.u;
  return (u16)((u + 0x7fffu + ((u >> 16) & 1u)) >> 16);   // RNE
}
__device__ __forceinline__ float bf2f(u16 h) {
  union { unsigned u; float f; } x; x.u = ((unsigned)h) << 16;
  return x.f;
}

// Raw barrier: waits LDS ops only (lgkmcnt), does NOT drain vmcnt.
// Global stores (X_states) keep flowing under later phases.
__device__ __forceinline__ void bar_lgkm() {
  __builtin_amdgcn_sched_barrier(0);
  asm volatile("s_waitcnt lgkmcnt(0)" ::: "memory");
  __builtin_amdgcn_sched_barrier(0);
  __builtin_amdgcn_s_barrier();
  __builtin_amdgcn_sched_barrier(0);
}
__device__ __forceinline__ void bar_only() {
  __builtin_amdgcn_sched_barrier(0);
  __builtin_amdgcn_s_barrier();
  __builtin_amdgcn_sched_barrier(0);
}

// ---- K0: W1/W2/W3 (f32, [k][n]) -> MFMA-fragment-packed bf16 ----
// Element (L, n, k):  nt=n>>4, ml=n&15, ks=k>>5, g=(k>>3)&3, j=k&7,
// lane = g*16+ml.  dst u16 index = ((L*16+nt)*8+ks)*512 + lane*8 + j.
// A wave's A-fragment load (nt,ks) is then 64 lanes x 16B = 1 KB contiguous.
__global__ void k_prep(const float* __restrict__ W1, const float* __restrict__ W2,
                       const float* __restrict__ W3, u16* __restrict__ wt) {
  const int b = blockIdx.x;
  const int m = b >> 8;          // which matrix
  const int n = b & 255;         // output unit
  const int k = threadIdx.x;     // input unit
  const float* W = (m == 0) ? W1 : ((m == 1) ? W2 : W3);
  const int nt = n >> 4, ml = n & 15;
  const int ks = k >> 5, g = (k >> 3) & 3, j = k & 7;
  const int lane = g * 16 + ml;
  wt[(((m * 16 + nt) * 8 + ks) << 9) + lane * 8 + j] = f2bf(W[k * 256 + n]);
}

// ---- K1: fused X-concat/X_states write + 3-layer bf16 MFMA MLP + head ----
// r5-champion geometry: 512 threads (8 waves), RB=128. Wave w owns
// n in [w*32, w*32+32) for ALL 128 rows -> weights read once per block
// (1.5 GB L2 total). acc[2][8] = 64 AGPR + 64 arch = 128-reg cap of
// launch_bounds(512,4) -> 2 blocks/CU. Packed-fragment weight loads
// (1KB contiguous per instruction). Full (row&15) chunk-XOR swizzle.
// Raw lgkm-only barriers: X_states stores never drained at a barrier.
__global__ __launch_bounds__(512, 4) void k_main(
    const float* __restrict__ g_emb, const float* __restrict__ cand,
    const int* __restrict__ bidx,
    const float* __restrict__ b1, const float* __restrict__ b2,
    const float* __restrict__ b3, const float* __restrict__ Wf,
    const float* __restrict__ bfp, const u16* __restrict__ wt,
    float* __restrict__ out)
{
  __shared__ __align__(16) u16 hbuf[RB * HID];   // 64 KB, chunk-XOR swizzled
  __shared__ float bias_s[3 * HID];
  __shared__ float wf_s[HID];
  __shared__ float bf_s;

  const int tid = threadIdx.x;
  const int r0  = blockIdx.x * RB;

  if (tid < HID) {
    bias_s[tid]           = b1[tid];
    bias_s[HID + tid]     = b2[tid];
    bias_s[2 * HID + tid] = b3[tid];
    wf_s[tid]             = Wf[tid];
    if (tid == 0) bf_s = bfp[0];
  }

  // ---- stage X (concat) into LDS bf16 swizzled; write X_states f32 ----
  {
    const int kc   = tid & 31;    // 16B chunk (8 elems) within the 256-col row
    const int row0 = tid >> 5;    // 0..15
    char* l0 = (char*)hbuf;
    int bpre[8];
    #pragma unroll
    for (int i = 0; i < 8; ++i)
      bpre[i] = bidx[r0 + row0 + i * 16];   // break dependent-load chain
    #pragma unroll
    for (int i = 0; i < 8; ++i) {
      const int row = row0 + i * 16;        // 0..127
      const int r   = r0 + row;
      const float* src;
      if (kc < 16) {
        src = g_emb + (size_t)bpre[i] * EMB + kc * 8;
      } else {
        src = cand + (size_t)r * EMB + (kc - 16) * 8;
      }
      f32x4 v0 = *(const f32x4*)(src);
      f32x4 v1 = *(const f32x4*)(src + 4);
      float* dst = out + OUT_XS + (size_t)r * (2 * EMB) + kc * 8;
      *(f32x4*)dst       = v0;   // async: never waited before a barrier
      *(f32x4*)(dst + 4) = v1;
      bf16x8 hv;
      hv[0] = (short)f2bf(v0.x); hv[1] = (short)f2bf(v0.y);
      hv[2] = (short)f2bf(v0.z); hv[3] = (short)f2bf(v0.w);
      hv[4] = (short)f2bf(v1.x); hv[5] = (short)f2bf(v1.y);
      hv[6] = (short)f2bf(v1.z); hv[7] = (short)f2bf(v1.w);
      *(bf16x8*)(l0 + row * 512 + ((kc * 16) ^ ((row & 15) << 4))) = hv;
    }
  }
  bar_lgkm();

  // ---- 3 MFMA layers, in place ----
  const int lane = tid & 63;
  const int w    = tid >> 6;          // 0..7
  const int ml   = lane & 15;
  const int g    = lane >> 4;         // 0..3
  const int wn0  = w * 32;            // n-offset: 2 tiles of 16 per wave

  const int swz    = ml << 4;                 // row-swizzle ((rf*16+ml)&15 == ml)
  const int bofs   = (g * 16) ^ swz;          // k-chunk xor per lane
  char* const hb   = (char*)hbuf;
  char* const hbr  = hb + (size_t)ml * 512;   // B-read base (rows rf*16+ml)

  #pragma unroll
  for (int L = 0; L < 3; ++L) {
    // packed fragments: frag (nt=w*2+nf, ks) at ((L*16+nt)*8+ks)*1024 + lane*16
    const char* wl  = (const char*)wt + ((size_t)(L * 16 + w * 2) * 8) * 1024 + lane * 16;
    const float* bs = bias_s + L * HID;

    f32x4 acc[2][8];   // [nf][rf] = 64 AGPR
    #pragma unroll
    for (int nf = 0; nf < 2; ++nf)
      #pragma unroll
      for (int rf = 0; rf < 8; ++rf)
        acc[nf][rf] = (f32x4){0.f, 0.f, 0.f, 0.f};

    __builtin_amdgcn_s_setprio(1);
    #pragma unroll
    for (int ks = 0; ks < 8; ++ks) {
      bf16x8 a[2];
      #pragma unroll
      for (int nf = 0; nf < 2; ++nf)
        a[nf] = *(const bf16x8*)(wl + (nf * 8 + ks) * 1024);         // 1KB coalesced
      #pragma unroll
      for (int rh = 0; rh < 2; ++rh) {
        bf16x8 bq[4];
        #pragma unroll
        for (int rj = 0; rj < 4; ++rj)
          bq[rj] = *(const bf16x8*)(hbr + (rh * 4 + rj) * 8192 + ((ks * 64) ^ bofs));
        #pragma unroll
        for (int nf = 0; nf < 2; ++nf)
          #pragma unroll
          for (int rj = 0; rj < 4; ++rj)
            acc[nf][rh * 4 + rj] = __builtin_amdgcn_mfma_f32_16x16x32_bf16(
                a[nf], bq[rj], acc[nf][rh * 4 + rj], 0, 0, 0);
      }
    }
    __builtin_amdgcn_s_setprio(0);
    // every wave's ds_reads are consumed by its MFMAs before it can reach
    // the barrier -> plain barrier suffices before in-place overwrite.
    bar_only();

    // epilogue: +bias, relu, ->bf16, packed b64 swizzled write (in place)
    #pragma unroll
    for (int nf = 0; nf < 2; ++nf) {
      const int n0 = wn0 + nf * 16 + g * 4;
      const f32x4 bb = *(const f32x4*)(bs + n0);
      #pragma unroll
      for (int rf = 0; rf < 8; ++rf) {
        const int r = rf * 16 + ml;
        bf16x4 hv;
        #pragma unroll
        for (int q = 0; q < 4; ++q) {
          float x = acc[nf][rf][q] + bb[q];
          x = fmaxf(x, 0.f);
          hv[q] = (short)f2bf(x);
        }
        *(bf16x4*)(hb + r * 512 + ((n0 * 2) ^ swz)) = hv;
      }
    }
    bar_lgkm();
  }

  // ---- head: logits = h3 @ Wf + bf ; e = exp(logit)  (full 256 k) ----
  {
    const int row  = tid >> 2;   // 0..127
    const int part = tid & 3;
    const int  swr = (row & 15) << 4;
    float sum = 0.f;
    #pragma unroll
    for (int i = 0; i < 8; ++i) {
      const int kc = part * 8 + i;            // 0..31: all 32 chunks
      bf16x8 hv = *(const bf16x8*)(hb + row * 512 + ((kc * 16) ^ swr));
      #pragma unroll
      for (int j = 0; j < 8; ++j)
        sum += bf2f((u16)hv[j]) * wf_s[kc * 8 + j];
    }
    sum += __shfl_xor(sum, 1);
    sum += __shfl_xor(sum, 2);
    if (part == 0) {
      const float logit = sum + bf_s;
      out[OUT_P + (size_t)(r0 + row)] = __expf(logit);
    }
  }
}

// ---- K2: denom[b] = segment_sum(e) via binary search (sorted batch_idx) ----
__global__ void k_denom(const float* __restrict__ e, const int* __restrict__ bidx,
                        float* __restrict__ denom)
{
  const int b = blockIdx.x;
  int lo = 0, hi = N_CAND;
  while (lo < hi) { int m = (lo + hi) >> 1; if (bidx[m] < b) lo = m + 1; else hi = m; }
  int lo2 = lo, hi2 = N_CAND;
  while (lo2 < hi2) { int m = (lo2 + hi2) >> 1; if (bidx[m] < b + 1) lo2 = m + 1; else hi2 = m; }
  float s = 0.f;
  for (int i = lo + (int)threadIdx.x; i < lo2; i += 64) s += e[i];
  #pragma unroll
  for (int off = 32; off > 0; off >>= 1) s += __shfl_down(s, off);
  if (threadIdx.x == 0) denom[b] = s;
}

// ---- K3: probs = e / denom[bidx] (in place) + g_emb copy ----
__global__ void k_post(const float* __restrict__ g_emb, const int* __restrict__ bidx,
                       const float* __restrict__ denom, float* __restrict__ out)
{
  const int i = blockIdx.x * 256 + threadIdx.x;
  const float e = out[OUT_P + (size_t)i];
  out[OUT_P + (size_t)i] = e / denom[bidx[i]];
  if (i < BGR * EMB) out[i] = g_emb[i];
}

extern "C" void kernel_launch(void* const* d_in, const int* in_sizes, int n_in,
                              void* d_out, int out_size, void* d_ws, size_t ws_size,
                              hipStream_t stream)
{
  const float* g_emb = (const float*)d_in[0];
  const float* cand  = (const float*)d_in[1];
  const float* W1    = (const float*)d_in[2];
  const float* b1    = (const float*)d_in[3];
  const float* W2    = (const float*)d_in[4];
  const float* b2    = (const float*)d_in[5];
  const float* W3    = (const float*)d_in[6];
  const float* b3    = (const float*)d_in[7];
  const float* Wf    = (const float*)d_in[8];
  const float* bfp   = (const float*)d_in[9];
  const int*   bidx  = (const int*)d_in[10];
  float* out = (float*)d_out;

  u16*   wt    = (u16*)d_ws;                                 // 3 * 128 KB bf16
  float* denom = (float*)((char*)d_ws + 3 * 65536 * 2);      // 2048 f32

  k_prep <<<768, 256, 0, stream>>>(W1, W2, W3, wt);
  k_main <<<NBLK, 512, 0, stream>>>(g_emb, cand, bidx, b1, b2, b3, Wf, bfp, wt, out);
  k_denom<<<BGR, 64, 0, stream>>>(out + OUT_P, bidx, denom);
  k_post <<<N_CAND / 256, 256, 0, stream>>>(g_emb, bidx, denom, out);
}